// Round 9
// baseline (634.098 us; speedup 1.0000x reference)
//
#include <hip/hip_runtime.h>

#define NN 100000
#define NE 3200000
#define NF 128
#define C1 32
#define C2 16
#define NG 64
#define BKT_W  128
#define NBKT   782          // ceil(NN/128)

// ---- workspace layout (4-byte element offsets) ----
// cntf+deg adjacent -> ONE memset covers all zeroed state.
#define OFF_CNTF  0              // 64 floats
#define OFF_DEG   64             // 100096 ints (padded to 128-mult; zeroed)
#define OFF_ROW   100160         // NN+1 ints -> 200161 (pad 200176)
#define OFF_CUR   200176         // NN ints  -> 300176
#define OFF_DIS   300176         // NN floats -> 400176
#define OFF_COL   400176         // NE ints -> 3,600,176
#define OFF_XS1   3600176        // NN*16 uints (16B-aligned) -> 5,200,176
#define OFF_XS2B  5200176        // NN*8 uints -> 6,000,176 (~24MB total)

// ---- bf16x2 pack/unpack (RNE) ----
__device__ __forceinline__ unsigned pack_bf2(float a, float b) {
    unsigned ua = __float_as_uint(a);
    unsigned ub = __float_as_uint(b);
    ua = (ua + 0x7fffu + ((ua >> 16) & 1u)) >> 16;
    ub = (ub + 0x7fffu + ((ub >> 16) & 1u)) & 0xffff0000u;
    return ua | ub;   // lo = a, hi = b
}
__device__ __forceinline__ float2 unpack_bf2(unsigned u) {
    return make_float2(__uint_as_float(u << 16), __uint_as_float(u & 0xffff0000u));
}
__device__ __forceinline__ void acc4(float4& a, uint2 q) {
    float2 f0 = unpack_bf2(q.x), f1 = unpack_bf2(q.y);
    a.x += f0.x; a.y += f0.y; a.z += f1.x; a.w += f1.y;
}

// ---------------- k_deg: degree histogram via global atomics ----------------
__global__ __launch_bounds__(512) void k_deg(
    const int* __restrict__ D, int* __restrict__ deg)
{
    int i = blockIdx.x * 512 + threadIdx.x;      // indexes int4
    if (i < NE / 4) {
        int4 d = ((const int4*)D)[i];
        atomicAdd(&deg[d.x], 1);
        atomicAdd(&deg[d.y], 1);
        atomicAdd(&deg[d.z], 1);
        atomicAdd(&deg[d.w], 1);
    }
}

// ---------------- k_rowsgemm: rowstart/cur/dis/cntf scan + GEMM1 ------------
// Phase R: block b owns nodes b*128..+127. bs = sum(deg[0..b*128)) strided
// (deg is 400KB, L2/L3-hot), local 128-scan -> rowstart, cur, dis, cntf.
// Phase G: xs1 = bf16x2{(x @ W1) * dis} for the SAME nodes, dis from LDS.
__global__ __launch_bounds__(256) void k_rowsgemm(
    const int* __restrict__ deg, const int* __restrict__ batch,
    int* __restrict__ rowstart, int* __restrict__ cur, float* __restrict__ dis,
    float* __restrict__ cntf,
    const float* __restrict__ x, const float* __restrict__ W1,
    unsigned* __restrict__ xs1)
{
    __shared__ float xls[128 * 33];
    __shared__ float wls[32 * 32];
    __shared__ float dloc[BKT_W];
    __shared__ float gcnt[NG];
    __shared__ int wsum[4];
    __shared__ int hs1;
    const int b = blockIdx.x;
    const int t = threadIdx.x;
    const int lane = t & 63, wv = t >> 6;

    if (t < NG) gcnt[t] = 0.f;

    // --- bs = sum(deg[0..b*128)), int4-strided + wave xor-reduce
    int acc = 0;
    {
        const int lim4 = (b * BKT_W) >> 2;
        const int4* dg4 = (const int4*)deg;
        for (int i = t; i < lim4; i += 256) {
            int4 q = dg4[i];
            acc += (q.x + q.y) + (q.z + q.w);
        }
    }
    #pragma unroll
    for (int off = 1; off < 64; off <<= 1) acc += __shfl_xor(acc, off, 64);
    if (lane == 0) wsum[wv] = acc;
    __syncthreads();
    const int bs = wsum[0] + wsum[1] + wsum[2] + wsum[3];

    // --- local 128-scan of deg (2-wave shuffle scan)
    int myd = 0, sc2 = 0;
    const int node0 = b * BKT_W;
    if (t < BKT_W) {
        int node = node0 + t;
        myd = (node < NN) ? deg[node] : 0;
        sc2 = myd;
        #pragma unroll
        for (int off = 1; off < 64; off <<= 1) {
            int v = __shfl_up(sc2, off, 64);
            if (lane >= off) sc2 += v;
        }
        if (t == 63) hs1 = sc2;
    }
    __syncthreads();
    if (t < BKT_W) {
        int excl = sc2 - myd + ((t >= 64) ? hs1 : 0);
        int node = node0 + t;
        float dv = rsqrtf((float)myd + 1.0f);
        dloc[t] = dv;
        if (node < NN) {
            rowstart[node] = bs + excl;
            cur[node]      = bs + excl;      // scatter cursor
            dis[node]      = dv;
            atomicAdd(&gcnt[batch[node]], 1.0f);
        }
    }
    if (b == 0 && t == 0) rowstart[NN] = NE;
    __syncthreads();
    if (t < NG && gcnt[t] != 0.f) atomicAdd(&cntf[t], gcnt[t]);

    // ---------------- Phase G: GEMM1 for nodes b*128..b*128+127 ------------
    const int tc = t & 7;
    const int tr = t >> 3;
    float a[4][4] = {};

    for (int k0 = 0; k0 < NF; k0 += 32) {
        {
            int i = t * 4;
            int kk = i >> 5, c = i & 31;
            *(float4*)&wls[kk * 32 + c] = *(const float4*)&W1[(k0 + kk) * C1 + c];
        }
        #pragma unroll
        for (int r = 0; r < 4; ++r) {
            int n = (t >> 3) + r * 32;
            int j = (t & 7) * 4;
            int node = node0 + n;
            float4 v = make_float4(0.f, 0.f, 0.f, 0.f);
            if (node < NN) v = *(const float4*)&x[(long long)node * NF + k0 + j];
            xls[n * 33 + j + 0] = v.x;
            xls[n * 33 + j + 1] = v.y;
            xls[n * 33 + j + 2] = v.z;
            xls[n * 33 + j + 3] = v.w;
        }
        __syncthreads();
        #pragma unroll 8
        for (int kk = 0; kk < 32; ++kk) {
            float4 w = *(const float4*)&wls[kk * 32 + tc * 4];
            #pragma unroll
            for (int i = 0; i < 4; ++i) {
                float xv = xls[(tr * 4 + i) * 33 + kk];
                a[i][0] = fmaf(xv, w.x, a[i][0]);
                a[i][1] = fmaf(xv, w.y, a[i][1]);
                a[i][2] = fmaf(xv, w.z, a[i][2]);
                a[i][3] = fmaf(xv, w.w, a[i][3]);
            }
        }
        __syncthreads();
    }
    #pragma unroll
    for (int i = 0; i < 4; ++i) {
        int node = node0 + tr * 4 + i;
        if (node < NN) {
            float dv = dloc[tr * 4 + i];
            uint2 o;
            o.x = pack_bf2(a[i][0] * dv, a[i][1] * dv);
            o.y = pack_bf2(a[i][2] * dv, a[i][3] * dv);
            *(uint2*)&xs1[node * 16 + tc * 2] = o;
        }
    }
}

// ---------------- k_scatter: CSR fill via atomic cursors --------------------
__global__ __launch_bounds__(512) void k_scatter(
    const int* __restrict__ S, const int* __restrict__ D,
    int* __restrict__ cur, int* __restrict__ colidx)
{
    int i = blockIdx.x * 512 + threadIdx.x;      // indexes int4
    if (i < NE / 4) {
        int4 s = ((const int4*)S)[i];
        int4 d = ((const int4*)D)[i];
        int p0 = atomicAdd(&cur[d.x], 1);
        int p1 = atomicAdd(&cur[d.y], 1);
        int p2 = atomicAdd(&cur[d.z], 1);
        int p3 = atomicAdd(&cur[d.w], 1);
        colidx[p0] = s.x;
        colidx[p1] = s.y;
        colidx[p2] = s.z;
        colidx[p3] = s.w;
    }
}

// ---------------- gather layer1 + fused GEMM2 epilogue ----------------------
// Block 0 also seeds out[g] = b2·lw + lb (consumed by gather2's atomicAdds).
__global__ __launch_bounds__(256) void k_gather1(
    const unsigned* __restrict__ xs1, const int* __restrict__ colidx,
    const int* __restrict__ rowstart, const float* __restrict__ dis,
    const float* __restrict__ b1, const float* __restrict__ W2,
    const float* __restrict__ b2, const float* __restrict__ lw,
    const float* __restrict__ lb, float* __restrict__ out,
    unsigned* __restrict__ xs2b)
{
    __shared__ float w2s[C1 * C2];
    __shared__ float hrow[32 * 33];
    const int t = threadIdx.x;
    if (t < 128) *(float4*)&w2s[t * 4] = *(const float4*)&W2[t * 4];
    if (blockIdx.x == 0 && t < NG) {
        float s = lb[0];
        #pragma unroll
        for (int k = 0; k < C2; ++k) s = fmaf(b2[k], lw[k], s);
        out[t] = s;                         // bias fold; gather2 accumulates
    }
    const int l = t & 7;
    const int n = t >> 3;
    const int v = blockIdx.x * 32 + n;   // NN = 100000 = 3125*32 exactly

    const int start = rowstart[v];
    const int num = rowstart[v + 1] - start;
    const int* __restrict__ cp = &colidx[start];
    const uint2* __restrict__ tb = (const uint2*)xs1;   // row v = tb[v*8 + l]
    float4 a0 = make_float4(0.f, 0.f, 0.f, 0.f);
    float4 a1 = a0, a2 = a0, a3 = a0;
    acc4(a0, tb[v * 8 + l]);                            // self loop
    int i = 0;
    if (num >= 8) {
        int idx[8];
        #pragma unroll
        for (int j = 0; j < 8; ++j) idx[j] = cp[j];
        for (; i + 16 <= num; i += 8) {
            int nx[8];
            #pragma unroll
            for (int j = 0; j < 8; ++j) nx[j] = cp[i + 8 + j];
            uint2 q[8];
            #pragma unroll
            for (int j = 0; j < 8; ++j) q[j] = tb[idx[j] * 8 + l];
            acc4(a0, q[0]); acc4(a1, q[1]); acc4(a2, q[2]); acc4(a3, q[3]);
            acc4(a0, q[4]); acc4(a1, q[5]); acc4(a2, q[6]); acc4(a3, q[7]);
            #pragma unroll
            for (int j = 0; j < 8; ++j) idx[j] = nx[j];
        }
        {   // drain the pipelined 8
            uint2 q[8];
            #pragma unroll
            for (int j = 0; j < 8; ++j) q[j] = tb[idx[j] * 8 + l];
            acc4(a0, q[0]); acc4(a1, q[1]); acc4(a2, q[2]); acc4(a3, q[3]);
            acc4(a0, q[4]); acc4(a1, q[5]); acc4(a2, q[6]); acc4(a3, q[7]);
            i += 8;
        }
    }
    for (; i < num; ++i) acc4(a0, tb[cp[i] * 8 + l]);
    float ax = (a0.x + a1.x) + (a2.x + a3.x);
    float ay = (a0.y + a1.y) + (a2.y + a3.y);
    float az = (a0.z + a1.z) + (a2.z + a3.z);
    float aw = (a0.w + a1.w) + (a2.w + a3.w);
    const float dv = dis[v];

    hrow[n * 33 + l * 4 + 0] = fmaxf(fmaf(ax, dv, b1[l * 4 + 0]), 0.f);
    hrow[n * 33 + l * 4 + 1] = fmaxf(fmaf(ay, dv, b1[l * 4 + 1]), 0.f);
    hrow[n * 33 + l * 4 + 2] = fmaxf(fmaf(az, dv, b1[l * 4 + 2]), 0.f);
    hrow[n * 33 + l * 4 + 3] = fmaxf(fmaf(aw, dv, b1[l * 4 + 3]), 0.f);
    __syncthreads();

    // GEMM2 epilogue: lane l computes output cols 2l, 2l+1
    const float* hr = &hrow[n * 33];
    float s0 = 0.f, s1 = 0.f;
    #pragma unroll
    for (int k = 0; k < 32; ++k) {
        float hv = hr[k];
        s0 = fmaf(hv, w2s[k * C2 + 2 * l + 0], s0);
        s1 = fmaf(hv, w2s[k * C2 + 2 * l + 1], s1);
    }
    xs2b[v * 8 + l] = pack_bf2(s0 * dv, s1 * dv);
}

// ---------------- gather layer2 + mean-pool + final (algebraic fusion) ------
// out[g] = sum_v (h2[v]·lw)/cnt[g] + const, const seeded by gather1.
__global__ __launch_bounds__(256) void k_gather2(
    const unsigned* __restrict__ xs2b, const int* __restrict__ colidx,
    const int* __restrict__ rowstart, const float* __restrict__ dis,
    const int* __restrict__ batch, const float* __restrict__ cntf,
    const float* __restrict__ lw, float* __restrict__ out)
{
    __shared__ float sg[NG];
    const int t = threadIdx.x;
    if (t < NG) sg[t] = 0.f;
    __syncthreads();

    const int l = t & 3;
    const int n = t >> 2;                 // 0..63
    const int v = blockIdx.x * 64 + n;
    const bool valid = v < NN;

    float4 r = make_float4(0.f, 0.f, 0.f, 0.f);
    int g = 0;
    if (valid) {
        const int start = rowstart[v];
        const int num = rowstart[v + 1] - start;
        const int* __restrict__ cp = &colidx[start];
        const uint2* __restrict__ tb = (const uint2*)xs2b;  // row v = tb[v*4 + l]
        float4 a0 = make_float4(0.f, 0.f, 0.f, 0.f);
        float4 a1 = a0, a2 = a0, a3 = a0;
        acc4(a0, tb[v * 4 + l]);                            // self loop
        int i = 0;
        if (num >= 8) {
            int idx[8];
            #pragma unroll
            for (int j = 0; j < 8; ++j) idx[j] = cp[j];
            for (; i + 16 <= num; i += 8) {
                int nx[8];
                #pragma unroll
                for (int j = 0; j < 8; ++j) nx[j] = cp[i + 8 + j];
                uint2 q[8];
                #pragma unroll
                for (int j = 0; j < 8; ++j) q[j] = tb[idx[j] * 4 + l];
                acc4(a0, q[0]); acc4(a1, q[1]); acc4(a2, q[2]); acc4(a3, q[3]);
                acc4(a0, q[4]); acc4(a1, q[5]); acc4(a2, q[6]); acc4(a3, q[7]);
                #pragma unroll
                for (int j = 0; j < 8; ++j) idx[j] = nx[j];
            }
            {
                uint2 q[8];
                #pragma unroll
                for (int j = 0; j < 8; ++j) q[j] = tb[idx[j] * 4 + l];
                acc4(a0, q[0]); acc4(a1, q[1]); acc4(a2, q[2]); acc4(a3, q[3]);
                acc4(a0, q[4]); acc4(a1, q[5]); acc4(a2, q[6]); acc4(a3, q[7]);
                i += 8;
            }
        }
        for (; i < num; ++i) acc4(a0, tb[cp[i] * 4 + l]);
        float dv = dis[v];
        g = batch[v];
        r.x = ((a0.x + a1.x) + (a2.x + a3.x)) * dv;
        r.y = ((a0.y + a1.y) + (a2.y + a3.y)) * dv;
        r.z = ((a0.z + a1.z) + (a2.z + a3.z)) * dv;
        r.w = ((a0.w + a1.w) + (a2.w + a3.w)) * dv;
    }

    // per-node dot with lw, 4-lane reduce, pre-divide by cnt, LDS accumulate
    float part = r.x * lw[l * 4 + 0] + r.y * lw[l * 4 + 1]
               + r.z * lw[l * 4 + 2] + r.w * lw[l * 4 + 3];
    part += __shfl_xor(part, 1, 64);
    part += __shfl_xor(part, 2, 64);
    if (valid && l == 0) {
        float c = fmaxf(cntf[g], 1.0f);
        atomicAdd(&sg[g], part / c);
    }
    __syncthreads();
    if (t < NG && sg[t] != 0.f) atomicAdd(&out[t], sg[t]);
}

extern "C" void kernel_launch(void* const* d_in, const int* in_sizes, int n_in,
                              void* d_out, int out_size, void* d_ws, size_t ws_size,
                              hipStream_t stream) {
    const float* x     = (const float*)d_in[0];
    const int*   ei    = (const int*)d_in[1];
    const int*   batch = (const int*)d_in[2];
    const float* W1    = (const float*)d_in[3];
    const float* b1    = (const float*)d_in[4];
    const float* W2    = (const float*)d_in[5];
    const float* b2    = (const float*)d_in[6];
    const float* lw    = (const float*)d_in[7];
    const float* lb    = (const float*)d_in[8];
    float* out = (float*)d_out;

    float*    wsf = (float*)d_ws;
    int*      wsi = (int*)d_ws;
    unsigned* wsu = (unsigned*)d_ws;

    float*    cntf     = wsf + OFF_CNTF;
    int*      deg      = wsi + OFF_DEG;
    int*      rowstart = wsi + OFF_ROW;
    int*      cur      = wsi + OFF_CUR;
    float*    dis      = wsf + OFF_DIS;
    int*      colidx   = wsi + OFF_COL;
    unsigned* xs1      = wsu + OFF_XS1;
    unsigned* xs2b     = wsu + OFF_XS2B;

    const int* S = ei;            // edge_index[0] (src)
    const int* D = ei + NE;       // edge_index[1] (dst)

    hipMemsetAsync(wsi + OFF_CNTF, 0, (64 + 100096) * sizeof(int), stream);

    const int EB = (NE / 4 + 511) / 512;   // 1563 blocks of 512
    k_deg      <<<EB, 512, 0, stream>>>(D, deg);
    k_rowsgemm <<<NBKT, 256, 0, stream>>>(deg, batch, rowstart, cur, dis, cntf, x, W1, xs1);
    k_scatter  <<<EB, 512, 0, stream>>>(S, D, cur, colidx);
    k_gather1  <<<NN / 32, 256, 0, stream>>>(xs1, colidx, rowstart, dis, b1, W2,
                                             b2, lw, lb, out, xs2b);
    k_gather2  <<<(NN + 63) / 64, 256, 0, stream>>>(xs2b, colidx, rowstart, dis,
                                                    batch, cntf, lw, out);
}

// Round 10
// 249.127 us; speedup vs baseline: 2.5453x; 2.5453x over previous
//
#include <hip/hip_runtime.h>

#define NN 100000
#define NE 3200000
#define NF 128
#define C1 32
#define C2 16
#define NG 64
#define BKT_SH 7
#define BKT_W  128
#define NBKT   782          // ceil(NN/128)
#define CH     8192         // edges per partition chunk
#define NW     391          // ceil(NE/CH)
#define RSTR   784          // runstart row stride (783 used)
#define MAPCAP 6400         // per-bucket flattened-edge capacity (mean 4092, sd 64)
#define XSTR   (NN * 8)     // xs2b replica stride (uints) = 3.2MB -> fits XCD L2

// ---- workspace layout (4-byte element offsets) ----
// bcnt/cntf adjacent -> ONE memset covers all zeroed state.
#define OFF_BCNT  0            // 1024 ints (782 used)
#define OFF_CNTF  2048         // NG floats (within zeroed 0..2304)
#define OFF_RUN   2304         // NW*RSTR = 306,544 -> 308,848
#define OFF_ROW   308848       // NN+1 -> 408,849 (pad 408,864)
#define OFF_DIS   408864       // NN -> 508,864
#define OFF_EDG   508864       // NE uints -> 3,708,864 (16B aligned)
// xs1 aliases edgebuf: ONLY legal because fillfused (last edgebuf reader) and
// gemm1 (xs1 writer) are SEPARATE kernels — do not fuse them (r5 fault).
#define OFF_XS1   OFF_EDG                  // NN*16 uints bf16x2 cols 0..31
#define OFF_XS2B  (OFF_EDG + NE)           // 8 replicas x NN*8 uints -> +6.4M
#define OFF_COL   (OFF_XS2B + 8 * XSTR)    // NE ints -> ~53MB total

// ---- bf16x2 pack/unpack (RNE) ----
__device__ __forceinline__ unsigned pack_bf2(float a, float b) {
    unsigned ua = __float_as_uint(a);
    unsigned ub = __float_as_uint(b);
    ua = (ua + 0x7fffu + ((ua >> 16) & 1u)) >> 16;
    ub = (ub + 0x7fffu + ((ub >> 16) & 1u)) & 0xffff0000u;
    return ua | ub;   // lo = a, hi = b
}
__device__ __forceinline__ float2 unpack_bf2(unsigned u) {
    return make_float2(__uint_as_float(u << 16), __uint_as_float(u & 0xffff0000u));
}
__device__ __forceinline__ void acc4(float4& a, uint2 q) {
    float2 f0 = unpack_bf2(q.x), f1 = unpack_bf2(q.y);
    a.x += f0.x; a.y += f0.y; a.z += f1.x; a.w += f1.y;
}

// ---------------- k_part: per-chunk counting sort by bucket -----------------
// Sort-based build: coalesced colidx writes. r9 measured the alternative
// (global-atomic scatter): 15x write amplification, 310us. Keep the sort.
__global__ __launch_bounds__(512) void k_part(
    const int* __restrict__ S, const int* __restrict__ D,
    unsigned* __restrict__ edgebuf, int* __restrict__ runstart,
    int* __restrict__ bcnt)
{
    __shared__ int lhist[1024];
    __shared__ int lstart[1024];
    __shared__ int lcur[NBKT];
    __shared__ int wsum[8];
    __shared__ unsigned lsort[CH];
    const int w = blockIdx.x;
    const int t = threadIdx.x;
    const int e0 = w * CH;
    const int n = min(CH, NE - e0);     // 8192 or 5120 (last); both %4 == 0
    const int n4 = n >> 2;
    const int4* __restrict__ S4 = (const int4*)(S + e0);
    const int4* __restrict__ D4 = (const int4*)(D + e0);

    for (int i = t; i < 1024; i += 512) lhist[i] = 0;
    __syncthreads();
    for (int i = t; i < n4; i += 512) {
        int4 d = D4[i];
        atomicAdd(&lhist[(unsigned)d.x >> BKT_SH], 1);
        atomicAdd(&lhist[(unsigned)d.y >> BKT_SH], 1);
        atomicAdd(&lhist[(unsigned)d.z >> BKT_SH], 1);
        atomicAdd(&lhist[(unsigned)d.w >> BKT_SH], 1);
    }
    __syncthreads();
    for (int i = t; i < NBKT; i += 512) atomicAdd(&bcnt[i], lhist[i]);

    int c0 = lhist[t * 2 + 0], c1 = lhist[t * 2 + 1];
    int ts = c0 + c1;
    const int lane = t & 63, wv = t >> 6;
    int sc = ts;
    #pragma unroll
    for (int off = 1; off < 64; off <<= 1) {
        int v = __shfl_up(sc, off, 64);
        if (lane >= off) sc += v;
    }
    if (lane == 63) wsum[wv] = sc;
    __syncthreads();
    int wo = 0;
    #pragma unroll
    for (int i = 0; i < 8; ++i) wo += (i < wv) ? wsum[i] : 0;
    int excl = sc - ts + wo;
    lstart[t * 2 + 0] = excl;
    lstart[t * 2 + 1] = excl + c0;
    __syncthreads();

    for (int i = t; i < 783; i += 512) runstart[w * RSTR + i] = lstart[i];
    for (int i = t; i < NBKT; i += 512) lcur[i] = lstart[i];
    __syncthreads();
    for (int i = t; i < n4; i += 512) {
        int4 s = S4[i];
        int4 d = D4[i];
        { int p = atomicAdd(&lcur[(unsigned)d.x >> BKT_SH], 1);
          lsort[p] = ((unsigned)s.x << BKT_SH) | ((unsigned)d.x & (BKT_W - 1)); }
        { int p = atomicAdd(&lcur[(unsigned)d.y >> BKT_SH], 1);
          lsort[p] = ((unsigned)s.y << BKT_SH) | ((unsigned)d.y & (BKT_W - 1)); }
        { int p = atomicAdd(&lcur[(unsigned)d.z >> BKT_SH], 1);
          lsort[p] = ((unsigned)s.z << BKT_SH) | ((unsigned)d.z & (BKT_W - 1)); }
        { int p = atomicAdd(&lcur[(unsigned)d.w >> BKT_SH], 1);
          lsort[p] = ((unsigned)s.w << BKT_SH) | ((unsigned)d.w & (BKT_W - 1)); }
    }
    __syncthreads();
    {
        uint4* __restrict__ eb4 = (uint4*)(edgebuf + e0);
        const uint4* __restrict__ ls4 = (const uint4*)lsort;
        for (int i = t; i < n4; i += 512) eb4[i] = ls4[i];
    }
}

// ---------------- fused per-bucket fill (bscan folded, LDS edge staging) ----
// Also accumulates per-graph node counts -> cntf (for the algebraic final).
__global__ __launch_bounds__(256) void k_fillfused(
    const unsigned* __restrict__ edgebuf, const int* __restrict__ runstart,
    const int* __restrict__ bcnt, const int* __restrict__ batch,
    int* __restrict__ rowstart, float* __restrict__ dis, int* __restrict__ colidx,
    float* __restrict__ cntf)
{
    __shared__ int rl[NW];
    __shared__ int pfx[NW];
    __shared__ int basea[NW];
    __shared__ unsigned short map[MAPCAP];
    __shared__ unsigned ebuf[MAPCAP];     // staged edges: global read ONCE
    __shared__ int lcnt[BKT_W];
    __shared__ int lcur[BKT_W];
    __shared__ float gcnt[NG];
    __shared__ int wsum[4];
    __shared__ int hs1;
    const int b = blockIdx.x;
    const int t = threadIdx.x;
    const int lane = t & 63, wv = t >> 6;

    if (t < NG) gcnt[t] = 0.f;

    // --- bs = sum(bcnt[0..b)) : strided + full-wave xor reduce
    int accp = 0;
    for (int i = t; i < b; i += 256) accp += bcnt[i];
    #pragma unroll
    for (int off = 1; off < 64; off <<= 1) accp += __shfl_xor(accp, off, 64);
    if (lane == 0) wsum[wv] = accp;

    for (int w = t; w < NW; w += 256) {
        int s0 = runstart[w * RSTR + b];
        int s1 = runstart[w * RSTR + b + 1];
        basea[w] = s0;
        rl[w] = s1 - s0;
    }
    if (t < BKT_W) lcnt[t] = 0;
    __syncthreads();
    const int bs = wsum[0] + wsum[1] + wsum[2] + wsum[3];

    // --- scan rl (391 entries, 2/thread, wave-shuffle)
    int w0 = t * 2;
    int c0 = (w0 < NW) ? rl[w0] : 0;
    int c1 = (w0 + 1 < NW) ? rl[w0 + 1] : 0;
    int ts = c0 + c1;
    int sc = ts;
    #pragma unroll
    for (int off = 1; off < 64; off <<= 1) {
        int v = __shfl_up(sc, off, 64);
        if (lane >= off) sc += v;
    }
    __syncthreads();                       // all bs-reads done before wsum reuse
    if (lane == 63) wsum[wv] = sc;
    __syncthreads();
    int wo = 0;
    #pragma unroll
    for (int i = 0; i < 4; ++i) wo += (i < wv) ? wsum[i] : 0;
    const int total = wsum[0] + wsum[1] + wsum[2] + wsum[3];
    int excl0 = sc - ts + wo;
    if (w0 < NW)     pfx[w0]     = excl0;
    if (w0 + 1 < NW) pfx[w0 + 1] = excl0 + c0;
    __syncthreads();

    for (int w = t; w < NW; w += 256) {
        int p = pfx[w], len = rl[w];
        basea[w] = w * CH + basea[w] - p;
        for (int i = 0; i < len; ++i) map[p + i] = (unsigned short)w;
    }
    __syncthreads();
    // count pass: read each edge ONCE from global, stage in LDS
    for (int j = t; j < total; j += 256) {
        unsigned p = edgebuf[basea[map[j]] + j];
        ebuf[j] = p;
        atomicAdd(&lcnt[p & (BKT_W - 1)], 1);
    }
    __syncthreads();

    // --- 128-wide scan of lcnt: 2-wave shuffle scan, 1 barrier
    int myc = 0, sc2 = 0;
    if (t < BKT_W) {
        myc = lcnt[t];
        sc2 = myc;
        #pragma unroll
        for (int off = 1; off < 64; off <<= 1) {
            int v = __shfl_up(sc2, off, 64);
            if (lane >= off) sc2 += v;
        }
        if (t == 63) hs1 = sc2;
    }
    __syncthreads();
    if (t < BKT_W) {
        int excl = sc2 - myc + ((t >= 64) ? hs1 : 0);
        int node = b * BKT_W + t;
        if (node < NN) {
            rowstart[node] = bs + excl;
            dis[node] = rsqrtf((float)myc + 1.0f);
            atomicAdd(&gcnt[batch[node]], 1.0f);   // per-graph node count
        }
        lcur[t] = bs + excl;
    }
    if (b == 0 && t == 0) rowstart[NN] = NE;
    __syncthreads();
    if (t < NG && gcnt[t] != 0.f) atomicAdd(&cntf[t], gcnt[t]);
    // scatter pass from LDS-staged edges (coalesced-region colidx writes)
    for (int j = t; j < total; j += 256) {
        unsigned p = ebuf[j];
        int pos = atomicAdd(&lcur[p & (BKT_W - 1)], 1);
        colidx[pos] = (int)(p >> BKT_SH);
    }
}

// ---------------- GEMM1: xs1 = bf16x2{(x @ W1) * dis}, 64B/node row ---------
__global__ __launch_bounds__(256) void k_gemm1(
    const float* __restrict__ x, const float* __restrict__ W1,
    const float* __restrict__ dis,
    unsigned* __restrict__ xs1)
{
    __shared__ float xls[128 * 33];
    __shared__ float wls[32 * 32];
    const int t = threadIdx.x;
    const int tc = t & 7;
    const int tr = t >> 3;
    const int base = blockIdx.x * 128;

    float a[4][4] = {};

    for (int k0 = 0; k0 < NF; k0 += 32) {
        {
            int i = t * 4;
            int kk = i >> 5, c = i & 31;
            *(float4*)&wls[kk * 32 + c] = *(const float4*)&W1[(k0 + kk) * C1 + c];
        }
        #pragma unroll
        for (int r = 0; r < 4; ++r) {
            int n = (t >> 3) + r * 32;
            int j = (t & 7) * 4;
            int node = base + n;
            float4 v = make_float4(0.f, 0.f, 0.f, 0.f);
            if (node < NN) v = *(const float4*)&x[(long long)node * NF + k0 + j];
            xls[n * 33 + j + 0] = v.x;
            xls[n * 33 + j + 1] = v.y;
            xls[n * 33 + j + 2] = v.z;
            xls[n * 33 + j + 3] = v.w;
        }
        __syncthreads();
        #pragma unroll 8
        for (int kk = 0; kk < 32; ++kk) {
            float4 w = *(const float4*)&wls[kk * 32 + tc * 4];
            #pragma unroll
            for (int i = 0; i < 4; ++i) {
                float xv = xls[(tr * 4 + i) * 33 + kk];
                a[i][0] = fmaf(xv, w.x, a[i][0]);
                a[i][1] = fmaf(xv, w.y, a[i][1]);
                a[i][2] = fmaf(xv, w.z, a[i][2]);
                a[i][3] = fmaf(xv, w.w, a[i][3]);
            }
        }
        __syncthreads();
    }
    #pragma unroll
    for (int i = 0; i < 4; ++i) {
        int node = base + tr * 4 + i;
        if (node < NN) {
            float dv = dis[node];
            uint2 o;
            o.x = pack_bf2(a[i][0] * dv, a[i][1] * dv);
            o.y = pack_bf2(a[i][2] * dv, a[i][3] * dv);
            *(uint2*)&xs1[node * 16 + tc * 2] = o;
        }
    }
}

// ---------------- gather layer1 + fused GEMM2 epilogue ----------------------
// Block 0 seeds out[g] = b2·lw + lb. Writes xs2b 8x (one replica per XCD L2).
__global__ __launch_bounds__(256) void k_gather1(
    const unsigned* __restrict__ xs1, const int* __restrict__ colidx,
    const int* __restrict__ rowstart, const float* __restrict__ dis,
    const float* __restrict__ b1, const float* __restrict__ W2,
    const float* __restrict__ b2, const float* __restrict__ lw,
    const float* __restrict__ lb, float* __restrict__ out,
    unsigned* __restrict__ xs2b)
{
    __shared__ float w2s[C1 * C2];
    __shared__ float hrow[32 * 33];
    const int t = threadIdx.x;
    if (t < 128) *(float4*)&w2s[t * 4] = *(const float4*)&W2[t * 4];
    if (blockIdx.x == 0 && t < NG) {
        float s = lb[0];
        #pragma unroll
        for (int k = 0; k < C2; ++k) s = fmaf(b2[k], lw[k], s);
        out[t] = s;                         // bias fold; gather2 accumulates
    }
    const int l = t & 7;
    const int n = t >> 3;
    const int v = blockIdx.x * 32 + n;   // NN = 100000 = 3125*32 exactly

    const int start = rowstart[v];
    const int num = rowstart[v + 1] - start;
    const int* __restrict__ cp = &colidx[start];
    const uint2* __restrict__ tb = (const uint2*)xs1;   // row v = tb[v*8 + l]
    float4 a0 = make_float4(0.f, 0.f, 0.f, 0.f);
    float4 a1 = a0, a2 = a0, a3 = a0;
    acc4(a0, tb[v * 8 + l]);                            // self loop
    int i = 0;
    if (num >= 8) {
        int idx[8];
        #pragma unroll
        for (int j = 0; j < 8; ++j) idx[j] = cp[j];
        for (; i + 16 <= num; i += 8) {
            int nx[8];
            #pragma unroll
            for (int j = 0; j < 8; ++j) nx[j] = cp[i + 8 + j];
            uint2 q[8];
            #pragma unroll
            for (int j = 0; j < 8; ++j) q[j] = tb[idx[j] * 8 + l];
            acc4(a0, q[0]); acc4(a1, q[1]); acc4(a2, q[2]); acc4(a3, q[3]);
            acc4(a0, q[4]); acc4(a1, q[5]); acc4(a2, q[6]); acc4(a3, q[7]);
            #pragma unroll
            for (int j = 0; j < 8; ++j) idx[j] = nx[j];
        }
        {   // drain the pipelined 8
            uint2 q[8];
            #pragma unroll
            for (int j = 0; j < 8; ++j) q[j] = tb[idx[j] * 8 + l];
            acc4(a0, q[0]); acc4(a1, q[1]); acc4(a2, q[2]); acc4(a3, q[3]);
            acc4(a0, q[4]); acc4(a1, q[5]); acc4(a2, q[6]); acc4(a3, q[7]);
            i += 8;
        }
    }
    for (; i < num; ++i) acc4(a0, tb[cp[i] * 8 + l]);
    float ax = (a0.x + a1.x) + (a2.x + a3.x);
    float ay = (a0.y + a1.y) + (a2.y + a3.y);
    float az = (a0.z + a1.z) + (a2.z + a3.z);
    float aw = (a0.w + a1.w) + (a2.w + a3.w);
    const float dv = dis[v];

    hrow[n * 33 + l * 4 + 0] = fmaxf(fmaf(ax, dv, b1[l * 4 + 0]), 0.f);
    hrow[n * 33 + l * 4 + 1] = fmaxf(fmaf(ay, dv, b1[l * 4 + 1]), 0.f);
    hrow[n * 33 + l * 4 + 2] = fmaxf(fmaf(az, dv, b1[l * 4 + 2]), 0.f);
    hrow[n * 33 + l * 4 + 3] = fmaxf(fmaf(aw, dv, b1[l * 4 + 3]), 0.f);
    __syncthreads();

    // GEMM2 epilogue: lane l computes output cols 2l, 2l+1
    const float* hr = &hrow[n * 33];
    float s0 = 0.f, s1 = 0.f;
    #pragma unroll
    for (int k = 0; k < 32; ++k) {
        float hv = hr[k];
        s0 = fmaf(hv, w2s[k * C2 + 2 * l + 0], s0);
        s1 = fmaf(hv, w2s[k * C2 + 2 * l + 1], s1);
    }
    unsigned packed = pack_bf2(s0 * dv, s1 * dv);
    #pragma unroll
    for (int c = 0; c < 8; ++c)
        xs2b[c * XSTR + v * 8 + l] = packed;    // 8 replicas
}

// ---------------- gather layer2 + mean-pool + final (algebraic fusion) ------
// Reads the XCD-local xs2b replica (blockIdx%8 tracks XCD on MI355X).
// out[g] = sum_v (h2[v]·lw)/cnt[g] + const, const seeded by gather1.
__global__ __launch_bounds__(256) void k_gather2(
    const unsigned* __restrict__ xs2b, const int* __restrict__ colidx,
    const int* __restrict__ rowstart, const float* __restrict__ dis,
    const int* __restrict__ batch, const float* __restrict__ cntf,
    const float* __restrict__ lw, float* __restrict__ out)
{
    __shared__ float sg[NG];
    const int t = threadIdx.x;
    if (t < NG) sg[t] = 0.f;
    __syncthreads();

    const int l = t & 3;
    const int n = t >> 2;                 // 0..63
    const int v = blockIdx.x * 64 + n;
    const bool valid = v < NN;

    float4 r = make_float4(0.f, 0.f, 0.f, 0.f);
    int g = 0;
    if (valid) {
        const int start = rowstart[v];
        const int num = rowstart[v + 1] - start;
        const int* __restrict__ cp = &colidx[start];
        const uint2* __restrict__ tb =
            (const uint2*)(xs2b + (blockIdx.x & 7) * XSTR);  // XCD-local copy
        float4 a0 = make_float4(0.f, 0.f, 0.f, 0.f);
        float4 a1 = a0, a2 = a0, a3 = a0;
        acc4(a0, tb[v * 4 + l]);                            // self loop
        int i = 0;
        if (num >= 8) {
            int idx[8];
            #pragma unroll
            for (int j = 0; j < 8; ++j) idx[j] = cp[j];
            for (; i + 16 <= num; i += 8) {
                int nx[8];
                #pragma unroll
                for (int j = 0; j < 8; ++j) nx[j] = cp[i + 8 + j];
                uint2 q[8];
                #pragma unroll
                for (int j = 0; j < 8; ++j) q[j] = tb[idx[j] * 4 + l];
                acc4(a0, q[0]); acc4(a1, q[1]); acc4(a2, q[2]); acc4(a3, q[3]);
                acc4(a0, q[4]); acc4(a1, q[5]); acc4(a2, q[6]); acc4(a3, q[7]);
                #pragma unroll
                for (int j = 0; j < 8; ++j) idx[j] = nx[j];
            }
            {
                uint2 q[8];
                #pragma unroll
                for (int j = 0; j < 8; ++j) q[j] = tb[idx[j] * 4 + l];
                acc4(a0, q[0]); acc4(a1, q[1]); acc4(a2, q[2]); acc4(a3, q[3]);
                acc4(a0, q[4]); acc4(a1, q[5]); acc4(a2, q[6]); acc4(a3, q[7]);
                i += 8;
            }
        }
        for (; i < num; ++i) acc4(a0, tb[cp[i] * 4 + l]);
        float dv = dis[v];
        g = batch[v];
        r.x = ((a0.x + a1.x) + (a2.x + a3.x)) * dv;
        r.y = ((a0.y + a1.y) + (a2.y + a3.y)) * dv;
        r.z = ((a0.z + a1.z) + (a2.z + a3.z)) * dv;
        r.w = ((a0.w + a1.w) + (a2.w + a3.w)) * dv;
    }

    // per-node dot with lw, 4-lane reduce, pre-divide by cnt, LDS accumulate
    float part = r.x * lw[l * 4 + 0] + r.y * lw[l * 4 + 1]
               + r.z * lw[l * 4 + 2] + r.w * lw[l * 4 + 3];
    part += __shfl_xor(part, 1, 64);
    part += __shfl_xor(part, 2, 64);
    if (valid && l == 0) {
        float c = fmaxf(cntf[g], 1.0f);
        atomicAdd(&sg[g], part / c);
    }
    __syncthreads();
    if (t < NG && sg[t] != 0.f) atomicAdd(&out[t], sg[t]);
}

extern "C" void kernel_launch(void* const* d_in, const int* in_sizes, int n_in,
                              void* d_out, int out_size, void* d_ws, size_t ws_size,
                              hipStream_t stream) {
    const float* x     = (const float*)d_in[0];
    const int*   ei    = (const int*)d_in[1];
    const int*   batch = (const int*)d_in[2];
    const float* W1    = (const float*)d_in[3];
    const float* b1    = (const float*)d_in[4];
    const float* W2    = (const float*)d_in[5];
    const float* b2    = (const float*)d_in[6];
    const float* lw    = (const float*)d_in[7];
    const float* lb    = (const float*)d_in[8];
    float* out = (float*)d_out;

    float*    wsf = (float*)d_ws;
    int*      wsi = (int*)d_ws;
    unsigned* wsu = (unsigned*)d_ws;

    int*      bcnt     = wsi + OFF_BCNT;
    float*    cntf     = wsf + OFF_CNTF;
    int*      runstart = wsi + OFF_RUN;
    int*      rowstart = wsi + OFF_ROW;
    float*    dis      = wsf + OFF_DIS;
    unsigned* edgebuf  = wsu + OFF_EDG;
    unsigned* xs1      = wsu + OFF_XS1;    // aliases edgebuf (dead after fillfused)
    unsigned* xs2b     = wsu + OFF_XS2B;
    int*      colidx   = wsi + OFF_COL;

    const int* S = ei;            // edge_index[0] (src)
    const int* D = ei + NE;       // edge_index[1] (dst)

    hipMemsetAsync(wsi + OFF_BCNT, 0, 2304 * sizeof(int), stream);  // bcnt+cntf

    k_part       <<<NW, 512, 0, stream>>>(S, D, edgebuf, runstart, bcnt);
    k_fillfused  <<<NBKT, 256, 0, stream>>>(edgebuf, runstart, bcnt, batch,
                                            rowstart, dis, colidx, cntf);
    k_gemm1      <<<(NN + 127) / 128, 256, 0, stream>>>(x, W1, dis, xs1);
    k_gather1    <<<NN / 32, 256, 0, stream>>>(xs1, colidx, rowstart, dis, b1, W2,
                                               b2, lw, lb, out, xs2b);
    k_gather2    <<<(NN + 63) / 64, 256, 0, stream>>>(xs2b, colidx, rowstart, dis,
                                                      batch, cntf, lw, out);
}